// Round 1
// baseline (1865.670 us; speedup 1.0000x reference)
//
#include <hip/hip_runtime.h>
#include <math.h>

#define N_PED 768
#define NW 12  // 768/64 words per adjacency row

// ---------------- ws layout (bytes) ----------------
// A      : [16][768] double   @ 0        (98304)
// P      : [33] double        @ 98304    (264)  -> w2eff[16], b1[16], c0
// adjw   : [768*12] u64       @ 98568    (73728)
// idx    : [768] int          @ 172296   (3072)
// pool   : [16][768] float    @ 175368   (49152)
// total 224520 bytes

// K1: per-pedestrian features -> A[o][n] = sum_k g1_w[o,k]*F[n,k]  (f64)
__global__ __launch_bounds__(256) void k1_prep(
    const float* __restrict__ va, const float* __restrict__ vr,
    const float* __restrict__ velw, const float* __restrict__ velb,
    const float* __restrict__ g1w, const float* __restrict__ g1b,
    const float* __restrict__ gam, const float* __restrict__ bet,
    const float* __restrict__ g2w, const float* __restrict__ g2b,
    double* __restrict__ A, double* __restrict__ P) {
  int n = blockIdx.x * 256 + threadIdx.x;
  if (n >= N_PED) return;
  double F[32];
#pragma unroll
  for (int c = 0; c < 2; ++c)
#pragma unroll
    for (int t = 0; t < 8; ++t)
      F[c * 8 + t] = (double)va[(c * 8 + t) * N_PED + n];
#pragma unroll
  for (int o = 0; o < 2; ++o)
#pragma unroll
    for (int t = 0; t < 8; ++t)
      F[(2 + o) * 8 + t] = (double)velb[o]
          + (double)velw[o * 2 + 0] * (double)vr[(0 + t) * N_PED + n]
          + (double)velw[o * 2 + 1] * (double)vr[(8 + t) * N_PED + n];
  for (int o = 0; o < 16; ++o) {
    double s = 0.0;
#pragma unroll
    for (int k = 0; k < 32; ++k) s += (double)g1w[o * 32 + k] * F[k];
    A[o * N_PED + n] = s;
  }
  if (n < 16) {
    const double inv_std = 1.0 / sqrt(1.0 + 1e-5);
    P[n] = (double)g2w[n] * inv_std * (double)gam[n];  // w2eff
    P[16 + n] = (double)g1b[n];                        // b1
  }
  if (n == 0) {
    double c0 = (double)g2b[0];
    for (int o = 0; o < 16; ++o) c0 += (double)g2w[o] * (double)bet[o];
    P[32] = c0;
  }
}

// K2: pairwise dist_mean (f64) -> strict-lower adjacency bits, ballot-packed
__global__ __launch_bounds__(256) void k2_dist(
    const double* __restrict__ A, const double* __restrict__ P,
    unsigned long long* __restrict__ adjw) {
  int gw = blockIdx.x * 4 + (threadIdx.x >> 6);
  int lane = threadIdx.x & 63;
  int r = gw / NW, j = gw % NW;
  int c = j * 64 + lane;
  double x1 = 0.0, x2 = 0.0;
#pragma unroll
  for (int o = 0; o < 16; ++o) {
    double s = A[o * N_PED + r] - A[o * N_PED + c];
    double b = P[16 + o], w2 = P[o];
    x1 += w2 * fmax(s + b, 0.0);
    x2 += w2 * fmax(b - s, 0.0);
  }
  double c0 = P[32];
  double dist = 0.5 * (exp(x1 + c0) + exp(x2 + c0));
  bool bit = (c < r) && (dist <= 1.0);
  unsigned long long word = __ballot(bit ? 1 : 0);
  if (lane == 0) adjw[r * NW + j] = word;
}

// K3: faithful serial relabeling, single wave, union-find in LDS.
// Semantics per edge (r,c) row-major: all nodes with label==labels[r] -> c.
// Equivalent per-row batch: cls=class(r); for c in C_r ascending, merge class
// currently NAMED c into cls; vacate all names in {L} u C_r \ {max}; name cls
// = max(C_r). owner[] maps name -> current class root (or -1).
__global__ __launch_bounds__(64) void k3_group(
    const unsigned long long* __restrict__ adjw, int* __restrict__ out_idx) {
  __shared__ int parentL[N_PED];
  __shared__ int nameL[N_PED];
  __shared__ int ownerL[N_PED];
  __shared__ int rowcmL[N_PED];
  volatile int* par = parentL;
  volatile int* nam = nameL;
  volatile int* own = ownerL;
  const int lane = threadIdx.x;

#pragma unroll
  for (int k = 0; k < NW; ++k) {
    int n = k * 64 + lane;
    parentL[n] = n; nameL[n] = n; ownerL[n] = n;
  }
  // per-row max edge column (or -1 if row empty)
  for (int k = 0; k < NW; ++k) {
    int r = k * 64 + lane;
    int cm = -1;
    for (int j = NW - 1; j >= 0; --j) {
      unsigned long long w = adjw[r * NW + j];
      if (w) { cm = j * 64 + (63 - __clzll((long long)w)); break; }
    }
    rowcmL[r] = cm;
  }

  for (int r = 1; r < N_PED; ++r) {
    int cm = rowcmL[r];
    if (cm < 0) continue;
    // load this row's 12 words (lanes 0..11), transpose to per-lane 12-bit mask
    unsigned long long w = (lane < NW) ? adjw[r * NW + lane] : 0ull;
    unsigned m12 = 0;
#pragma unroll
    for (int j = 0; j < NW; ++j) {
      unsigned long long wj = __shfl(w, j);
      m12 |= (unsigned)((wj >> lane) & 1ull) << j;
    }
    // find(r) with path halving (all lanes identical -> identical writes, safe)
    int cls = r;
    while (true) {
      int p = par[cls];
      if (p == cls) break;
      int gp = par[p];
      par[cls] = gp;
      cls = gp;
    }
    int L = nam[cls];
    // gather candidate roots: owner of each edge-column name (pre-row state)
    unsigned pend = 0;
    int cand[NW];
#pragma unroll
    for (int j = 0; j < NW; ++j) {
      cand[j] = -1;
      if ((m12 >> j) & 1u) {
        int t = own[j * 64 + lane];
        if (t >= 0) {
          while (true) { int p = par[t]; if (p == t) break; t = p; }  // defensive find
          if (t != cls) { cand[j] = t; pend |= 1u << j; }
        }
      }
    }
    // serially union each distinct candidate root under cls (<=767 total in run)
    while (true) {
      unsigned long long b = __ballot(pend != 0 ? 1 : 0);
      if (!b) break;
      int src = (int)__ffsll(b) - 1;
      int sel = -1;
#pragma unroll
      for (int j = 0; j < NW; ++j)
        if (sel < 0 && ((pend >> j) & 1u)) sel = cand[j];
      int tr = __shfl(sel, src);
      if (lane == src) par[tr] = cls;
#pragma unroll
      for (int j = 0; j < NW; ++j)
        if (((pend >> j) & 1u) && cand[j] == tr) pend &= ~(1u << j);
    }
    // vacate names of all edge columns except cm; vacate old name; rename
#pragma unroll
    for (int j = 0; j < NW; ++j) {
      int c = j * 64 + lane;
      if (((m12 >> j) & 1u) && c != cm) own[c] = -1;
    }
    if (lane == 0) { own[L] = -1; own[cm] = cls; nam[cls] = cm; }
  }

  // labels (reuse rowcmL), then rank labels ascending -> indices
#pragma unroll
  for (int k = 0; k < NW; ++k) {
    int n = k * 64 + lane;
    int x = n;
    while (true) { int p = par[x]; if (p == x) break; x = p; }
    rowcmL[n] = nam[x];
  }
#pragma unroll
  for (int k = 0; k < NW; ++k) ownerL[k * 64 + lane] = 0;
#pragma unroll
  for (int k = 0; k < NW; ++k) own[rowcmL[k * 64 + lane]] = 1;  // present flags
  int s = 0;
#pragma unroll
  for (int q = 0; q < NW; ++q) s += own[lane * NW + q];
  int inc = s;
  for (int d = 1; d < 64; d <<= 1) {
    int t = __shfl_up(inc, d);
    if (lane >= d) inc += t;
  }
  int run = inc - s;  // exclusive prefix of my value-segment
#pragma unroll
  for (int q = 0; q < NW; ++q) {
    run += own[lane * NW + q];
    nameL[lane * NW + q] = run - 1;  // rank of label value v (if present)
  }
#pragma unroll
  for (int k = 0; k < NW; ++k) {
    int n = k * 64 + lane;
    out_idx[n] = nameL[rowcmL[n]];
  }
}

// K4: deterministic group-mean pooling. block = one (c,t); thread = group slot g.
__global__ __launch_bounds__(768) void k4_pool(
    const float* __restrict__ vrel, const int* __restrict__ idx,
    float* __restrict__ pool) {
  int ct = blockIdx.x;
  int g = threadIdx.x;
  __shared__ int idxs[N_PED];
  __shared__ float vs[N_PED];
  idxs[g] = idx[g];
  vs[g] = vrel[ct * N_PED + g];
  __syncthreads();
  float s = 0.f;
  int cnt = 0;
  for (int n = 0; n < N_PED; ++n) {
    bool m = (idxs[n] == g);
    s += m ? vs[n] : 0.f;
    cnt += m ? 1 : 0;
  }
  pool[ct * N_PED + g] = s / fmaxf((float)cnt, 1.0f);
}

// K5: out[o,p,n] = (2*baseline(v_rel) + baseline(pool)[..,idx[n]]) / 3
__global__ __launch_bounds__(256) void k5_final(
    const float* __restrict__ vrel, const float* __restrict__ pool,
    const int* __restrict__ idx, const float* __restrict__ wt,
    const float* __restrict__ wc, float* __restrict__ out) {
  int i = blockIdx.x * 256 + threadIdx.x;
  if (i >= 5 * 12 * N_PED) return;
  int n = i % N_PED;
  int t_ = i / N_PED;
  int p = t_ % 12;
  int o = t_ / 12;
  int g = idx[n];
  float v1 = 0.f, v2 = 0.f;
#pragma unroll
  for (int c = 0; c < 2; ++c) {
    float u1 = 0.f, u2 = 0.f;
#pragma unroll
    for (int t = 0; t < 8; ++t) {
      float wtv = wt[t * 12 + p];
      u1 += wtv * vrel[(c * 8 + t) * N_PED + n];
      u2 += wtv * pool[(c * 8 + t) * N_PED + g];
    }
    float wcv = wc[c * 5 + o];
    v1 += wcv * u1;
    v2 += wcv * u2;
  }
  out[i] = (v1 + v2 + v1) / 3.0f;
}

extern "C" void kernel_launch(void* const* d_in, const int* in_sizes, int n_in,
                              void* d_out, int out_size, void* d_ws, size_t ws_size,
                              hipStream_t stream) {
  const float* va   = (const float*)d_in[0];
  const float* vr   = (const float*)d_in[1];
  const float* velw = (const float*)d_in[2];
  const float* velb = (const float*)d_in[3];
  const float* g1w  = (const float*)d_in[4];
  const float* g1b  = (const float*)d_in[5];
  const float* gam  = (const float*)d_in[6];
  const float* bet  = (const float*)d_in[7];
  const float* g2w  = (const float*)d_in[8];
  const float* g2b  = (const float*)d_in[9];
  const float* wt   = (const float*)d_in[10];
  const float* wc   = (const float*)d_in[11];
  float* out = (float*)d_out;

  char* ws = (char*)d_ws;
  double* A = (double*)(ws + 0);
  double* P = (double*)(ws + 98304);
  unsigned long long* adjw = (unsigned long long*)(ws + 98568);
  int* idx = (int*)(ws + 172296);
  float* pool = (float*)(ws + 175368);

  k1_prep<<<3, 256, 0, stream>>>(va, vr, velw, velb, g1w, g1b, gam, bet, g2w, g2b, A, P);
  k2_dist<<<2304, 256, 0, stream>>>(A, P, adjw);
  k3_group<<<1, 64, 0, stream>>>(adjw, idx);
  k4_pool<<<16, 768, 0, stream>>>(vr, idx, pool);
  k5_final<<<180, 256, 0, stream>>>(vr, pool, idx, wt, wc, out);
}

// Round 2
// 350.029 us; speedup vs baseline: 5.3300x; 5.3300x over previous
//
#include <hip/hip_runtime.h>
#include <math.h>

#define N_PED 768
#define NW 12  // 768/64 u64 words per adjacency row

// ---------------- ws layout (bytes) ----------------
// A      : [16][768] double   @ 0        (98304)
// P      : [33] double        @ 98304    (264)  -> w2eff[16], b1[16], c0
// adjw   : [768*12] u64       @ 98568    (73728)
// idx    : [768] int          @ 172296   (3072)
// pool   : [16][768] float    @ 175368   (49152)

// K1: per-pedestrian features -> A[o][n] = sum_k g1_w[o,k]*F[n,k]  (f64)
__global__ __launch_bounds__(256) void k1_prep(
    const float* __restrict__ va, const float* __restrict__ vr,
    const float* __restrict__ velw, const float* __restrict__ velb,
    const float* __restrict__ g1w, const float* __restrict__ g1b,
    const float* __restrict__ gam, const float* __restrict__ bet,
    const float* __restrict__ g2w, const float* __restrict__ g2b,
    double* __restrict__ A, double* __restrict__ P) {
  int n = blockIdx.x * 256 + threadIdx.x;
  if (n >= N_PED) return;
  double F[32];
#pragma unroll
  for (int c = 0; c < 2; ++c)
#pragma unroll
    for (int t = 0; t < 8; ++t)
      F[c * 8 + t] = (double)va[(c * 8 + t) * N_PED + n];
#pragma unroll
  for (int o = 0; o < 2; ++o)
#pragma unroll
    for (int t = 0; t < 8; ++t)
      F[(2 + o) * 8 + t] = (double)velb[o]
          + (double)velw[o * 2 + 0] * (double)vr[(0 + t) * N_PED + n]
          + (double)velw[o * 2 + 1] * (double)vr[(8 + t) * N_PED + n];
  for (int o = 0; o < 16; ++o) {
    double s = 0.0;
#pragma unroll
    for (int k = 0; k < 32; ++k) s += (double)g1w[o * 32 + k] * F[k];
    A[o * N_PED + n] = s;
  }
  if (n < 16) {
    const double inv_std = 1.0 / sqrt(1.0 + 1e-5);
    P[n] = (double)g2w[n] * inv_std * (double)gam[n];  // w2eff
    P[16 + n] = (double)g1b[n];                        // b1
  }
  if (n == 0) {
    double c0 = (double)g2b[0];
    for (int o = 0; o < 16; ++o) c0 += (double)g2w[o] * (double)bet[o];
    P[32] = c0;
  }
}

// K2: pairwise dist_mean (f64) -> strict-lower adjacency bits, ballot-packed
__global__ __launch_bounds__(256) void k2_dist(
    const double* __restrict__ A, const double* __restrict__ P,
    unsigned long long* __restrict__ adjw) {
  int gw = blockIdx.x * 4 + (threadIdx.x >> 6);
  int lane = threadIdx.x & 63;
  int r = gw / NW, j = gw % NW;
  int c = j * 64 + lane;
  double x1 = 0.0, x2 = 0.0;
#pragma unroll
  for (int o = 0; o < 16; ++o) {
    double s = A[o * N_PED + r] - A[o * N_PED + c];
    double b = P[16 + o], w2 = P[o];
    x1 += w2 * fmax(s + b, 0.0);
    x2 += w2 * fmax(b - s, 0.0);
  }
  double c0 = P[32];
  double dist = 0.5 * (exp(x1 + c0) + exp(x2 + c0));
  bool bit = (c < r) && (dist <= 1.0);
  unsigned long long word = __ballot(bit ? 1 : 0);
  if (lane == 0) adjw[r * NW + j] = word;
}

// K3: faithful serial relabeling via value-map T.
// Per row r (ascending), with C_r = edge columns, L = T[r], cm = max(C_r):
//   every T entry whose value is in {L} u C_r  ->  cm.
// (Exact collapse of the reference's per-edge "labels==labels[r] -> c"
//  sequence within a row, including the name-stealing corner cases.)
// T[768] lives in registers (12/lane, value v = k*64+lane); L via __shfl;
// membership via bit-packed adjacency preloaded into LDS.
__global__ __launch_bounds__(64) void k3_group(
    const unsigned long long* __restrict__ adjw, int* __restrict__ out_idx) {
  __shared__ unsigned int adjL[N_PED * 24];  // u32 view of 12 u64 per row
  __shared__ int rowcmL[N_PED];
  __shared__ int flagsL[N_PED];
  __shared__ int rankL[N_PED];
  const int lane = threadIdx.x;

  // preload adjacency (72 KB) into LDS
  const unsigned int* adjg = (const unsigned int*)adjw;
  for (int i = lane; i < N_PED * 24; i += 64) adjL[i] = adjg[i];
  __syncthreads();

  // per-row max edge column (or -1)
#pragma unroll
  for (int k = 0; k < NW; ++k) {
    int r = k * 64 + lane;
    int cm = -1;
    for (int j = 23; j >= 0; --j) {
      unsigned w = adjL[r * 24 + j];
      if (w) { cm = j * 32 + (31 - __clz(w)); break; }
    }
    rowcmL[r] = cm;
  }
  __syncthreads();

  // value map in registers: Treg[k] = T[k*64 + lane]
  int Treg[NW];
#pragma unroll
  for (int k = 0; k < NW; ++k) Treg[k] = k * 64 + lane;

#pragma unroll
  for (int k0 = 0; k0 < NW; ++k0) {
    for (int rl = (k0 == 0 ? 1 : 0); rl < 64; ++rl) {
      int r = k0 * 64 + rl;
      int cm = rowcmL[r];                 // uniform
      if (cm < 0) continue;               // uniform branch
      int L = __shfl(Treg[k0], rl);       // current label of node r
      int rb = r * 24;
#pragma unroll
      for (int k = 0; k < NW; ++k) {
        int v = Treg[k];
        unsigned w = adjL[rb + (v >> 5)];
        bool mem = (((w >> (v & 31)) & 1u) != 0u) | (v == L);
        Treg[k] = mem ? cm : Treg[k];
      }
    }
  }

  // rank distinct label values ascending -> group indices
#pragma unroll
  for (int k = 0; k < NW; ++k) flagsL[k * 64 + lane] = 0;
  __syncthreads();
#pragma unroll
  for (int k = 0; k < NW; ++k) flagsL[Treg[k]] = 1;
  __syncthreads();
  int f[NW];
  int s = 0;
#pragma unroll
  for (int q = 0; q < NW; ++q) { f[q] = flagsL[lane * NW + q]; s += f[q]; }
  int inc = s;
  for (int d = 1; d < 64; d <<= 1) {
    int t = __shfl_up(inc, d);
    if (lane >= d) inc += t;
  }
  int run = inc - s;  // exclusive prefix over lane segments
#pragma unroll
  for (int q = 0; q < NW; ++q) {
    run += f[q];
    rankL[lane * NW + q] = run - 1;
  }
  __syncthreads();
#pragma unroll
  for (int k = 0; k < NW; ++k) out_idx[k * 64 + lane] = rankL[Treg[k]];
}

// K4: deterministic group-mean pooling. block = one (c,t); thread = group slot g.
__global__ __launch_bounds__(768) void k4_pool(
    const float* __restrict__ vrel, const int* __restrict__ idx,
    float* __restrict__ pool) {
  int ct = blockIdx.x;
  int g = threadIdx.x;
  __shared__ int idxs[N_PED];
  __shared__ float vs[N_PED];
  idxs[g] = idx[g];
  vs[g] = vrel[ct * N_PED + g];
  __syncthreads();
  float s = 0.f;
  int cnt = 0;
  for (int n = 0; n < N_PED; ++n) {
    bool m = (idxs[n] == g);
    s += m ? vs[n] : 0.f;
    cnt += m ? 1 : 0;
  }
  pool[ct * N_PED + g] = s / fmaxf((float)cnt, 1.0f);
}

// K5: out[o,p,n] = (2*baseline(v_rel) + baseline(pool)[..,idx[n]]) / 3
__global__ __launch_bounds__(256) void k5_final(
    const float* __restrict__ vrel, const float* __restrict__ pool,
    const int* __restrict__ idx, const float* __restrict__ wt,
    const float* __restrict__ wc, float* __restrict__ out) {
  int i = blockIdx.x * 256 + threadIdx.x;
  if (i >= 5 * 12 * N_PED) return;
  int n = i % N_PED;
  int t_ = i / N_PED;
  int p = t_ % 12;
  int o = t_ / 12;
  int g = idx[n];
  float v1 = 0.f, v2 = 0.f;
#pragma unroll
  for (int c = 0; c < 2; ++c) {
    float u1 = 0.f, u2 = 0.f;
#pragma unroll
    for (int t = 0; t < 8; ++t) {
      float wtv = wt[t * 12 + p];
      u1 += wtv * vrel[(c * 8 + t) * N_PED + n];
      u2 += wtv * pool[(c * 8 + t) * N_PED + g];
    }
    float wcv = wc[c * 5 + o];
    v1 += wcv * u1;
    v2 += wcv * u2;
  }
  out[i] = (v1 + v2 + v1) / 3.0f;
}

extern "C" void kernel_launch(void* const* d_in, const int* in_sizes, int n_in,
                              void* d_out, int out_size, void* d_ws, size_t ws_size,
                              hipStream_t stream) {
  const float* va   = (const float*)d_in[0];
  const float* vr   = (const float*)d_in[1];
  const float* velw = (const float*)d_in[2];
  const float* velb = (const float*)d_in[3];
  const float* g1w  = (const float*)d_in[4];
  const float* g1b  = (const float*)d_in[5];
  const float* gam  = (const float*)d_in[6];
  const float* bet  = (const float*)d_in[7];
  const float* g2w  = (const float*)d_in[8];
  const float* g2b  = (const float*)d_in[9];
  const float* wt   = (const float*)d_in[10];
  const float* wc   = (const float*)d_in[11];
  float* out = (float*)d_out;

  char* ws = (char*)d_ws;
  double* A = (double*)(ws + 0);
  double* P = (double*)(ws + 98304);
  unsigned long long* adjw = (unsigned long long*)(ws + 98568);
  int* idx = (int*)(ws + 172296);
  float* pool = (float*)(ws + 175368);

  k1_prep<<<3, 256, 0, stream>>>(va, vr, velw, velb, g1w, g1b, gam, bet, g2w, g2b, A, P);
  k2_dist<<<2304, 256, 0, stream>>>(A, P, adjw);
  k3_group<<<1, 64, 0, stream>>>(adjw, idx);
  k4_pool<<<16, 768, 0, stream>>>(vr, idx, pool);
  k5_final<<<180, 256, 0, stream>>>(vr, pool, idx, wt, wc, out);
}